// Round 12
// baseline (96.399 us; speedup 1.0000x reference)
//
#include <hip/hip_runtime.h>
#include <hip/hip_fp16.h>

#define N_ROWS 8192
#define D_IN   4096
#define D_F    8192
#define PAIRS  2          // row-pairs per block (persistent pipeline depth)

typedef float f32x4 __attribute__((ext_vector_type(4)));
typedef int   i32x4 __attribute__((ext_vector_type(4)));

// DPP move on a packed u32: result lane gets source lane per CTRL.
template<int CTRL>
__device__ __forceinline__ unsigned dppu(unsigned v) {
  int r = __builtin_amdgcn_update_dpp(0, (int)v, CTRL, 0xF, 0xF, true);
  return (unsigned)r;
}

#define DPP_QUAD_XOR1       0xB1   // quad_perm(1,0,3,2)
#define DPP_QUAD_XOR2       0x4E   // quad_perm(2,3,0,1)
#define DPP_QUAD_XOR3       0x1B   // quad_perm(3,2,1,0)
#define DPP_ROW_HALF_MIRROR 0x141  // XOR 7 within 16-lane row
#define DPP_ROW_ROR8        0x128  // rotate 8 within row == XOR 8

__device__ __forceinline__ unsigned pkrtz(float lo, float hi) {
#if __has_builtin(__builtin_amdgcn_cvt_pkrtz)
  auto h = __builtin_amdgcn_cvt_pkrtz(lo, hi);   // __fp16 ext_vector(2)
  return __builtin_bit_cast(unsigned, h);
#else
  __half2 h = __floats2half2_rn(lo, hi);
  return __builtin_bit_cast(unsigned, h);
#endif
}
__device__ __forceinline__ float2 upk(unsigned u) {
  return __half22float2(__builtin_bit_cast(__half2, u));
}
// packed f16x2 math on u32 bit patterns (v_pk_add/sub/mul/fma_f16)
__device__ __forceinline__ unsigned padd(unsigned a, unsigned b) {
  return __builtin_bit_cast(unsigned,
      __hadd2(__builtin_bit_cast(__half2, a), __builtin_bit_cast(__half2, b)));
}
__device__ __forceinline__ unsigned psub(unsigned a, unsigned b) {
  return __builtin_bit_cast(unsigned,
      __hsub2(__builtin_bit_cast(__half2, a), __builtin_bit_cast(__half2, b)));
}
__device__ __forceinline__ unsigned pmul(unsigned a, unsigned b) {
  return __builtin_bit_cast(unsigned,
      __hmul2(__builtin_bit_cast(__half2, a), __builtin_bit_cast(__half2, b)));
}
__device__ __forceinline__ unsigned pfma(unsigned a, unsigned b, unsigned c) {
  return __builtin_bit_cast(unsigned,
      __hfma2(__builtin_bit_cast(__half2, a), __builtin_bit_cast(__half2, b),
              __builtin_bit_cast(__half2, c)));
}
// packed radix-4 Hadamard butterfly
__device__ __forceinline__ void h4p(unsigned& a, unsigned& b,
                                    unsigned& c, unsigned& d) {
  unsigned t0 = padd(a, b), t1 = psub(a, b), t2 = padd(c, d), t3 = psub(c, d);
  a = padd(t0, t2); c = psub(t0, t2);
  b = padd(t1, t3); d = psub(t1, t3);
}

// One block = PAIRS row-pairs, each pair packed f16x2 end-to-end (R11 core).
// New: cross-pair x prefetch — next pair's 8 nontemporal f32x4 loads issue
// right after degree-2's rad-multiply (xp's last use), landing under the
// degree-2 lane stages + stage + trip + gather/store (>> HBM latency).
__global__ __launch_bounds__(256) void srht_kernel(
    const float* __restrict__ x,
    const float* __restrict__ rad,
    const int* __restrict__ perm,
    float* __restrict__ out)
{
  __shared__ __align__(16) unsigned zp[D_IN];   // 16 KiB packed f16x2
  const int t    = threadIdx.x;
  const int lane = t & 63;
  const int wv   = t >> 6;
  const int pair0 = blockIdx.x * PAIRS;

  // packed butterfly signs for the 6 lane stages: (+1,+1) or (-1,-1)
  unsigned sg[6];
  #pragma unroll
  for (int s = 0; s < 6; ++s)
    sg[s] = (lane & (1 << s)) ? 0xBC00BC00u : 0x3C003C00u;

  const float S = 0.22272466f;   // cbrt(1/sqrt(8192)); S^3 = 0.011048543
  unsigned xp[4][4];
  f32x4 raw[8];
  uint4* z4 = reinterpret_cast<uint4*>(zp);

  // raw x load for pair p (nontemporal: zero reuse, keep L2 for perm)
  auto load_raw = [&](int p) {
    const f32x4* x0 = reinterpret_cast<const f32x4*>(x) +
                      (size_t)(p * 2) * (D_IN / 4);
    const f32x4* x1 = x0 + (D_IN / 4);
    #pragma unroll
    for (int c = 0; c < 4; ++c) {
      raw[c]     = __builtin_nontemporal_load(x0 + c * 256 + t);
      raw[4 + c] = __builtin_nontemporal_load(x1 + c * 256 + t);
    }
  };
  // scale + pack raw -> xp (raw regs die)
  auto pack_raw = [&]() {
    #pragma unroll
    for (int c = 0; c < 4; ++c) {
      xp[c][0] = pkrtz(S * raw[c][0], S * raw[4 + c][0]);
      xp[c][1] = pkrtz(S * raw[c][1], S * raw[4 + c][1]);
      xp[c][2] = pkrtz(S * raw[c][2], S * raw[4 + c][2]);
      xp[c][3] = pkrtz(S * raw[c][3], S * raw[4 + c][3]);
    }
  };

  // FWHT degree d: rad-mul, [optional next-pair x prefetch], reg h4p
  // (bits {0,1},{10,11}), 6 packed lane stages (bits {2..7}), perm
  // prefetch, stage, trip (bits {8,9}). Leaves zp gather-ready.
  auto fwht_stage_trip = [&](int d, i32x4* pp, bool pf, int next_pair) {
    unsigned v[4][4];
    const f32x4* rrow = reinterpret_cast<const f32x4*>(rad) + d * (D_IN / 4);
    #pragma unroll
    for (int c = 0; c < 4; ++c) {
      f32x4 rv = rrow[c * 256 + t];
      v[c][0] = pmul(xp[c][0], pkrtz(rv[0], rv[0]));
      v[c][1] = pmul(xp[c][1], pkrtz(rv[1], rv[1]));
      v[c][2] = pmul(xp[c][2], pkrtz(rv[2], rv[2]));
      v[c][3] = pmul(xp[c][3], pkrtz(rv[3], rv[3]));
    }
    if (pf) load_raw(next_pair);   // xp dead after rad-mul of d=2: 32 raw
                                   // regs replace 16 xp regs; loads land
                                   // under stages+stage+trip+gather.
    #pragma unroll
    for (int c = 0; c < 4; ++c) h4p(v[c][0], v[c][1], v[c][2], v[c][3]);
    #pragma unroll
    for (int i = 0; i < 4; ++i) h4p(v[0][i], v[1][i], v[2][i], v[3][i]);

    #pragma unroll
    for (int c = 0; c < 4; ++c)
      #pragma unroll
      for (int i = 0; i < 4; ++i) {     // XOR 1 (e-bit 2)
        unsigned p = dppu<DPP_QUAD_XOR1>(v[c][i]);
        v[c][i] = pfma(sg[0], v[c][i], p);
      }
    #pragma unroll
    for (int c = 0; c < 4; ++c)
      #pragma unroll
      for (int i = 0; i < 4; ++i) {     // XOR 2 (e-bit 3)
        unsigned p = dppu<DPP_QUAD_XOR2>(v[c][i]);
        v[c][i] = pfma(sg[1], v[c][i], p);
      }
    #pragma unroll
    for (int c = 0; c < 4; ++c)
      #pragma unroll
      for (int i = 0; i < 4; ++i) {     // XOR 4 (e-bit 4): XOR7 then XOR3
        unsigned p = dppu<DPP_QUAD_XOR3>(dppu<DPP_ROW_HALF_MIRROR>(v[c][i]));
        v[c][i] = pfma(sg[2], v[c][i], p);
      }
    #pragma unroll
    for (int c = 0; c < 4; ++c)
      #pragma unroll
      for (int i = 0; i < 4; ++i) {     // XOR 8 (e-bit 5)
        unsigned p = dppu<DPP_ROW_ROR8>(v[c][i]);
        v[c][i] = pfma(sg[3], v[c][i], p);
      }
    #pragma unroll
    for (int c = 0; c < 4; ++c)
      #pragma unroll
      for (int i = 0; i < 4; ++i) {     // XOR 16 (e-bit 6)
#if __has_builtin(__builtin_amdgcn_permlane16_swap)
        auto r = __builtin_amdgcn_permlane16_swap(v[c][i], v[c][i], false, false);
        unsigned p = (lane & 16) ? (unsigned)r[0] : (unsigned)r[1];
#else
        unsigned p = (unsigned)__shfl_xor((int)v[c][i], 16, 64);
#endif
        v[c][i] = pfma(sg[4], v[c][i], p);
      }
    #pragma unroll
    for (int c = 0; c < 4; ++c)
      #pragma unroll
      for (int i = 0; i < 4; ++i) {     // XOR 32 (e-bit 7)
#if __has_builtin(__builtin_amdgcn_permlane32_swap)
        auto r = __builtin_amdgcn_permlane32_swap(v[c][i], v[c][i], false, false);
        unsigned p = (lane & 32) ? (unsigned)r[0] : (unsigned)r[1];
#else
        unsigned p = (unsigned)__shfl_xor((int)v[c][i], 32, 64);
#endif
        v[c][i] = pfma(sg[5], v[c][i], p);
      }

    // prefetch first-half perm: lands during stage+trip (2 barriers of slack)
    const i32x4* p4 = reinterpret_cast<const i32x4*>(perm) + d * (D_F / 4);
    pp[0] = p4[0 * 256 + t];
    pp[1] = p4[1 * 256 + t];
    pp[2] = p4[2 * 256 + t];
    pp[3] = p4[3 * 256 + t];

    __syncthreads();   // previous gather has finished reading zp
    #pragma unroll
    for (int c = 0; c < 4; ++c) {
      uint4 u;
      u.x = v[c][0]; u.y = v[c][1]; u.z = v[c][2]; u.w = v[c][3];
      z4[c * 256 + t] = u;
    }
    __syncthreads();

    {   // trip: bits {8,9}, packed h4p, disjoint per-thread b128 RMW
      unsigned q[4][4];
      #pragma unroll
      for (int ww = 0; ww < 4; ++ww) {
        uint4 u = z4[wv * 256 + ww * 64 + lane];
        q[ww][0] = u.x; q[ww][1] = u.y; q[ww][2] = u.z; q[ww][3] = u.w;
      }
      #pragma unroll
      for (int i = 0; i < 4; ++i) h4p(q[0][i], q[1][i], q[2][i], q[3][i]);
      #pragma unroll
      for (int ww = 0; ww < 4; ++ww) {
        uint4 u;
        u.x = q[ww][0]; u.y = q[ww][1]; u.z = q[ww][2]; u.w = q[ww][3];
        z4[wv * 256 + ww * 64 + lane] = u;
      }
    }
    __syncthreads();
  };

  load_raw(pair0);
  pack_raw();

  #pragma unroll 1
  for (int k = 0; k < PAIRS; ++k) {
    const int n0 = (pair0 + k) * 2;
    const bool pf = (k + 1 < PAIRS);

    unsigned acc[32];
    #pragma unroll
    for (int i = 0; i < 32; ++i) acc[i] = 0x34003400u;  // f16x2(0.25,0.25)

    // ---- degrees 0,1: gather into packed acc ----
    #pragma unroll 1
    for (int d = 0; d < 2; ++d) {
      i32x4 pp[4];
      fwht_stage_trip(d, pp, false, 0);
      const i32x4* p4 = reinterpret_cast<const i32x4*>(perm) + d * (D_F / 4);
      #pragma unroll
      for (int it = 0; it < 8; ++it) {
        i32x4 p = (it < 4) ? pp[it] : p4[it * 256 + t];
        acc[it*4+0] = pmul(acc[it*4+0], zp[p[0]]);
        acc[it*4+1] = pmul(acc[it*4+1], zp[p[1]]);
        acc[it*4+2] = pmul(acc[it*4+2], zp[p[2]]);
        acc[it*4+3] = pmul(acc[it*4+3], zp[p[3]]);
      }
    }

    // ---- degree 2 (next-pair x prefetch inside), gather fused with
    //      nontemporal output stores ----
    {
      i32x4 pp[4];
      fwht_stage_trip(2, pp, pf, pair0 + k + 1);
      const i32x4* p4 = reinterpret_cast<const i32x4*>(perm) + 2 * (D_F / 4);
      f32x4* oa = reinterpret_cast<f32x4*>(out + (size_t)n0 * D_F);
      f32x4* ob = reinterpret_cast<f32x4*>(out + (size_t)(n0 + 1) * D_F);
      #pragma unroll
      for (int it = 0; it < 8; ++it) {
        i32x4 p = (it < 4) ? pp[it] : p4[it * 256 + t];
        unsigned a0 = pmul(acc[it*4+0], zp[p[0]]);
        unsigned a1 = pmul(acc[it*4+1], zp[p[1]]);
        unsigned a2 = pmul(acc[it*4+2], zp[p[2]]);
        unsigned a3 = pmul(acc[it*4+3], zp[p[3]]);
        float2 f0 = upk(a0), f1 = upk(a1), f2 = upk(a2), f3 = upk(a3);
        f32x4 va = {4.f * f0.x, 4.f * f1.x, 4.f * f2.x, 4.f * f3.x};
        f32x4 vb = {4.f * f0.y, 4.f * f1.y, 4.f * f2.y, 4.f * f3.y};
        __builtin_nontemporal_store(va, oa + it * 256 + t);
        __builtin_nontemporal_store(vb, ob + it * 256 + t);
      }
    }

    if (pf) pack_raw();   // raw -> xp for the next pair
  }
}

extern "C" void kernel_launch(void* const* d_in, const int* in_sizes, int n_in,
                              void* d_out, int out_size, void* d_ws, size_t ws_size,
                              hipStream_t stream) {
  const float* x   = (const float*)d_in[0];
  const float* rad = (const float*)d_in[1];
  const int* perm  = (const int*)d_in[2];
  float* out       = (float*)d_out;
  srht_kernel<<<N_ROWS / 2 / PAIRS, 256, 0, stream>>>(x, rad, perm, out);
}

// Round 13
// 83.200 us; speedup vs baseline: 1.1586x; 1.1586x over previous
//
#include <hip/hip_runtime.h>
#include <hip/hip_fp16.h>

#define N_ROWS 8192
#define D_IN   4096
#define D_F    8192

typedef float f32x4 __attribute__((ext_vector_type(4)));
typedef int   i32x4 __attribute__((ext_vector_type(4)));

// DPP move on a packed u32: result lane gets source lane per CTRL.
template<int CTRL>
__device__ __forceinline__ unsigned dppu(unsigned v) {
  int r = __builtin_amdgcn_update_dpp(0, (int)v, CTRL, 0xF, 0xF, true);
  return (unsigned)r;
}

#define DPP_QUAD_XOR1       0xB1   // quad_perm(1,0,3,2)
#define DPP_QUAD_XOR2       0x4E   // quad_perm(2,3,0,1)
#define DPP_QUAD_XOR3       0x1B   // quad_perm(3,2,1,0)
#define DPP_ROW_HALF_MIRROR 0x141  // XOR 7 within 16-lane row
#define DPP_ROW_ROR8        0x128  // rotate 8 within row == XOR 8

__device__ __forceinline__ unsigned pkrtz(float lo, float hi) {
#if __has_builtin(__builtin_amdgcn_cvt_pkrtz)
  auto h = __builtin_amdgcn_cvt_pkrtz(lo, hi);   // __fp16 ext_vector(2)
  return __builtin_bit_cast(unsigned, h);
#else
  __half2 h = __floats2half2_rn(lo, hi);
  return __builtin_bit_cast(unsigned, h);
#endif
}
__device__ __forceinline__ float2 upk(unsigned u) {
  return __half22float2(__builtin_bit_cast(__half2, u));
}
// packed f16x2 math on u32 bit patterns (v_pk_add/sub/mul/fma_f16)
__device__ __forceinline__ unsigned padd(unsigned a, unsigned b) {
  return __builtin_bit_cast(unsigned,
      __hadd2(__builtin_bit_cast(__half2, a), __builtin_bit_cast(__half2, b)));
}
__device__ __forceinline__ unsigned psub(unsigned a, unsigned b) {
  return __builtin_bit_cast(unsigned,
      __hsub2(__builtin_bit_cast(__half2, a), __builtin_bit_cast(__half2, b)));
}
__device__ __forceinline__ unsigned pmul(unsigned a, unsigned b) {
  return __builtin_bit_cast(unsigned,
      __hmul2(__builtin_bit_cast(__half2, a), __builtin_bit_cast(__half2, b)));
}
__device__ __forceinline__ unsigned pfma(unsigned a, unsigned b, unsigned c) {
  return __builtin_bit_cast(unsigned,
      __hfma2(__builtin_bit_cast(__half2, a), __builtin_bit_cast(__half2, b),
              __builtin_bit_cast(__half2, c)));
}
// packed radix-4 Hadamard butterfly
__device__ __forceinline__ void h4p(unsigned& a, unsigned& b,
                                    unsigned& c, unsigned& d) {
  unsigned t0 = padd(a, b), t1 = psub(a, b), t2 = padd(c, d), t3 = psub(c, d);
  a = padd(t0, t2); c = psub(t0, t2);
  b = padd(t1, t3); d = psub(t1, t3);
}

// One block = TWO rows packed as f16x2 in one u32 per element, END TO END
// (R11 structure — the validated best):
//  - bits {0,1},{10,11}: packed h4p in registers
//  - bits {2..7}: packed DPP / permlane lane stages (v_pk_fma_f16)
//  - bits {8,9}: packed b128 LDS RMW trip, conflict-free
//  - first-half perm prefetched into regs BEFORE the stage barrier
//  - degree-2 gather fused with nontemporal output stores
//  - nontemporal x loads (zero reuse; keeps L2 for perm)
__global__ __launch_bounds__(256) void srht_kernel(
    const float* __restrict__ x,
    const float* __restrict__ rad,
    const int* __restrict__ perm,
    float* __restrict__ out)
{
  __shared__ __align__(16) unsigned zp[D_IN];   // 16 KiB packed f16x2
  const int t    = threadIdx.x;
  const int lane = t & 63;
  const int wv   = t >> 6;
  const int n0   = blockIdx.x * 2;

  // packed butterfly signs for the 6 lane stages: (+1,+1) or (-1,-1)
  unsigned sg[6];
  #pragma unroll
  for (int s = 0; s < 6; ++s)
    sg[s] = (lane & (1 << s)) ? 0xBC00BC00u : 0x3C003C00u;

  // load + scale + pack x once (nontemporal; elem e = c*1024 + t*4 + i)
  const float S = 0.22272466f;   // cbrt(1/sqrt(8192)); S^3 = 0.011048543
  unsigned xp[4][4];
  {
    const f32x4* x0 = reinterpret_cast<const f32x4*>(x) + (size_t)n0 * (D_IN / 4);
    const f32x4* x1 = x0 + (D_IN / 4);
    #pragma unroll
    for (int c = 0; c < 4; ++c) {
      f32x4 a = __builtin_nontemporal_load(x0 + c * 256 + t);
      f32x4 b = __builtin_nontemporal_load(x1 + c * 256 + t);
      xp[c][0] = pkrtz(S * a[0], S * b[0]);
      xp[c][1] = pkrtz(S * a[1], S * b[1]);
      xp[c][2] = pkrtz(S * a[2], S * b[2]);
      xp[c][3] = pkrtz(S * a[3], S * b[3]);
    }
  }

  unsigned acc[32];
  #pragma unroll
  for (int k = 0; k < 32; ++k) acc[k] = 0x34003400u;   // f16x2(0.25, 0.25)

  uint4* z4 = reinterpret_cast<uint4*>(zp);

  // FWHT degree d: rad-mul, reg h4p (bits {0,1},{10,11}), 6 packed lane
  // stages (bits {2..7}), prefetch first-half perm, stage, trip (bits {8,9}).
  // Leaves zp gather-ready (barrier included).
  auto fwht_stage_trip = [&](int d, i32x4* pp) {
    unsigned v[4][4];
    const f32x4* rrow = reinterpret_cast<const f32x4*>(rad) + d * (D_IN / 4);
    #pragma unroll
    for (int c = 0; c < 4; ++c) {
      f32x4 rv = rrow[c * 256 + t];
      v[c][0] = pmul(xp[c][0], pkrtz(rv[0], rv[0]));
      v[c][1] = pmul(xp[c][1], pkrtz(rv[1], rv[1]));
      v[c][2] = pmul(xp[c][2], pkrtz(rv[2], rv[2]));
      v[c][3] = pmul(xp[c][3], pkrtz(rv[3], rv[3]));
    }
    #pragma unroll
    for (int c = 0; c < 4; ++c) h4p(v[c][0], v[c][1], v[c][2], v[c][3]);
    #pragma unroll
    for (int i = 0; i < 4; ++i) h4p(v[0][i], v[1][i], v[2][i], v[3][i]);

    #pragma unroll
    for (int c = 0; c < 4; ++c)
      #pragma unroll
      for (int i = 0; i < 4; ++i) {     // XOR 1 (e-bit 2)
        unsigned p = dppu<DPP_QUAD_XOR1>(v[c][i]);
        v[c][i] = pfma(sg[0], v[c][i], p);
      }
    #pragma unroll
    for (int c = 0; c < 4; ++c)
      #pragma unroll
      for (int i = 0; i < 4; ++i) {     // XOR 2 (e-bit 3)
        unsigned p = dppu<DPP_QUAD_XOR2>(v[c][i]);
        v[c][i] = pfma(sg[1], v[c][i], p);
      }
    #pragma unroll
    for (int c = 0; c < 4; ++c)
      #pragma unroll
      for (int i = 0; i < 4; ++i) {     // XOR 4 (e-bit 4): XOR7 then XOR3
        unsigned p = dppu<DPP_QUAD_XOR3>(dppu<DPP_ROW_HALF_MIRROR>(v[c][i]));
        v[c][i] = pfma(sg[2], v[c][i], p);
      }
    #pragma unroll
    for (int c = 0; c < 4; ++c)
      #pragma unroll
      for (int i = 0; i < 4; ++i) {     // XOR 8 (e-bit 5)
        unsigned p = dppu<DPP_ROW_ROR8>(v[c][i]);
        v[c][i] = pfma(sg[3], v[c][i], p);
      }
    #pragma unroll
    for (int c = 0; c < 4; ++c)
      #pragma unroll
      for (int i = 0; i < 4; ++i) {     // XOR 16 (e-bit 6)
#if __has_builtin(__builtin_amdgcn_permlane16_swap)
        auto r = __builtin_amdgcn_permlane16_swap(v[c][i], v[c][i], false, false);
        unsigned p = (lane & 16) ? (unsigned)r[0] : (unsigned)r[1];
#else
        unsigned p = (unsigned)__shfl_xor((int)v[c][i], 16, 64);
#endif
        v[c][i] = pfma(sg[4], v[c][i], p);
      }
    #pragma unroll
    for (int c = 0; c < 4; ++c)
      #pragma unroll
      for (int i = 0; i < 4; ++i) {     // XOR 32 (e-bit 7)
#if __has_builtin(__builtin_amdgcn_permlane32_swap)
        auto r = __builtin_amdgcn_permlane32_swap(v[c][i], v[c][i], false, false);
        unsigned p = (lane & 32) ? (unsigned)r[0] : (unsigned)r[1];
#else
        unsigned p = (unsigned)__shfl_xor((int)v[c][i], 32, 64);
#endif
        v[c][i] = pfma(sg[5], v[c][i], p);
      }

    // prefetch first-half perm: lands during stage+trip (2 barriers of slack)
    const i32x4* p4 = reinterpret_cast<const i32x4*>(perm) + d * (D_F / 4);
    pp[0] = p4[0 * 256 + t];
    pp[1] = p4[1 * 256 + t];
    pp[2] = p4[2 * 256 + t];
    pp[3] = p4[3 * 256 + t];

    __syncthreads();   // previous degree's gather has finished reading zp
    #pragma unroll
    for (int c = 0; c < 4; ++c) {
      uint4 u;
      u.x = v[c][0]; u.y = v[c][1]; u.z = v[c][2]; u.w = v[c][3];
      z4[c * 256 + t] = u;
    }
    __syncthreads();

    {   // trip: bits {8,9}, packed h4p, disjoint per-thread b128 RMW
      unsigned q[4][4];
      #pragma unroll
      for (int ww = 0; ww < 4; ++ww) {
        uint4 u = z4[wv * 256 + ww * 64 + lane];
        q[ww][0] = u.x; q[ww][1] = u.y; q[ww][2] = u.z; q[ww][3] = u.w;
      }
      #pragma unroll
      for (int i = 0; i < 4; ++i) h4p(q[0][i], q[1][i], q[2][i], q[3][i]);
      #pragma unroll
      for (int ww = 0; ww < 4; ++ww) {
        uint4 u;
        u.x = q[ww][0]; u.y = q[ww][1]; u.z = q[ww][2]; u.w = q[ww][3];
        z4[wv * 256 + ww * 64 + lane] = u;
      }
    }
    __syncthreads();
  };

  // ---- degrees 0,1: gather into packed acc ----
  #pragma unroll 1
  for (int d = 0; d < 2; ++d) {
    i32x4 pp[4];
    fwht_stage_trip(d, pp);
    const i32x4* p4 = reinterpret_cast<const i32x4*>(perm) + d * (D_F / 4);
    #pragma unroll
    for (int it = 0; it < 8; ++it) {
      i32x4 p = (it < 4) ? pp[it] : p4[it * 256 + t];
      acc[it*4+0] = pmul(acc[it*4+0], zp[p[0]]);
      acc[it*4+1] = pmul(acc[it*4+1], zp[p[1]]);
      acc[it*4+2] = pmul(acc[it*4+2], zp[p[2]]);
      acc[it*4+3] = pmul(acc[it*4+3], zp[p[3]]);
    }
  }

  // ---- degree 2: gather fused with nontemporal output stores ----
  {
    i32x4 pp[4];
    fwht_stage_trip(2, pp);
    const i32x4* p4 = reinterpret_cast<const i32x4*>(perm) + 2 * (D_F / 4);
    f32x4* oa = reinterpret_cast<f32x4*>(out + (size_t)n0 * D_F);
    f32x4* ob = reinterpret_cast<f32x4*>(out + (size_t)(n0 + 1) * D_F);
    #pragma unroll
    for (int it = 0; it < 8; ++it) {
      i32x4 p = (it < 4) ? pp[it] : p4[it * 256 + t];
      unsigned a0 = pmul(acc[it*4+0], zp[p[0]]);
      unsigned a1 = pmul(acc[it*4+1], zp[p[1]]);
      unsigned a2 = pmul(acc[it*4+2], zp[p[2]]);
      unsigned a3 = pmul(acc[it*4+3], zp[p[3]]);
      float2 f0 = upk(a0), f1 = upk(a1), f2 = upk(a2), f3 = upk(a3);
      f32x4 va = {4.f * f0.x, 4.f * f1.x, 4.f * f2.x, 4.f * f3.x};
      f32x4 vb = {4.f * f0.y, 4.f * f1.y, 4.f * f2.y, 4.f * f3.y};
      __builtin_nontemporal_store(va, oa + it * 256 + t);
      __builtin_nontemporal_store(vb, ob + it * 256 + t);
    }
  }
}

extern "C" void kernel_launch(void* const* d_in, const int* in_sizes, int n_in,
                              void* d_out, int out_size, void* d_ws, size_t ws_size,
                              hipStream_t stream) {
  const float* x   = (const float*)d_in[0];
  const float* rad = (const float*)d_in[1];
  const int* perm  = (const int*)d_in[2];
  float* out       = (float*)d_out;
  srht_kernel<<<N_ROWS / 2, 256, 0, stream>>>(x, rad, perm, out);
}